// Round 2
// baseline (259.314 us; speedup 1.0000x reference)
//
#include <hip/hip_runtime.h>

// GCN 2-layer, N=100000, E=1600000, dim 64, fp32 in/out.
// R2: (a) gather reverted to 2-node/wave broadcast-row form (R1 showed
// gather is line-SERVICE bound, not issue bound; 1-node/wave + shfl reduce
// cost +10us/pass). (b) gemm1 no longer needs dinv (scale moved into
// gather-1 as fmaf with dinv[src]) -> X@W1 fused into the partition launch
// (fat kernel, role by blockIdx) to overlap the two independent phases.
// (c) nontemporal loads/stores on all single-use streams (edges, pairs,
// srcs, gather outs, B16 in gemm2) to keep XW rows resident in per-XCD L2.
// Gather remains MSHR/L2-random-service bound (~76MB row misses per pass,
// XW 12.8MB >> 4MiB/XCD L2); bf16 rows are the byte floor given the
// 9.8e-3 absmax threshold.

#define BSHIFT 9             // bucket = dst >> 9  (512 nodes per bucket)
#define NPB 512              // nodes per bucket
#define NBUCK_MAX 256        // K = ceil(100000/512) = 196
#define CAP 10240            // slab capacity; E[edges/bucket]=8192, sd~90
#define CHUNK 4096

using frag16 = __attribute__((ext_vector_type(8))) short;   // 8 bf16
using fragf  = __attribute__((ext_vector_type(4))) float;   // 4 fp32 acc
typedef int          int4v   __attribute__((ext_vector_type(4)));
typedef unsigned int uint4v  __attribute__((ext_vector_type(4)));
typedef float        float4v __attribute__((ext_vector_type(4)));

__device__ __forceinline__ unsigned int f2bf(float f) {   // RNE fp32->bf16
    unsigned int u = __float_as_uint(f);
    return (u + 0x7fffu + ((u >> 16) & 1u)) >> 16;
}
__device__ __forceinline__ float bfl(unsigned int u) { return __uint_as_float(u << 16); }
__device__ __forceinline__ float bfh(unsigned int u) { return __uint_as_float(u & 0xffff0000u); }

// ---- fused: edge partition (blocks [0,pblocks)) + X@W1 bf16 gemm ----
// Partition: pack = (src << 9) | (dst & 511) into per-bucket slabs.
// Gemm role: 512 thr = two 64-row tiles; shared Wl; output UNSCALED bf16
// (dinv applied per-edge in gather-1, so no csr dependency).
__global__ __launch_bounds__(512) void fused_build_gemm1(
        const int* __restrict__ src, const int* __restrict__ dst,
        int* __restrict__ bcur, unsigned int* __restrict__ pairs, int e, int pblocks,
        const float* __restrict__ X, const float* __restrict__ W,
        unsigned short* __restrict__ Y16, int nrows) {
    __shared__ __align__(16) char smem[28672];
    const int t = threadIdx.x;

    if ((int)blockIdx.x < pblocks) {
        // ---------------- partition role (24.5KB LDS) ----------------
        int* cnt  = (int*)smem;
        int* offs = cnt + NBUCK_MAX;
        int* cur  = offs + NBUCK_MAX;
        int* base = cur + NBUCK_MAX;
        unsigned int*  sP = (unsigned int*)(base + NBUCK_MAX);   // CHUNK
        unsigned char* sB = (unsigned char*)(sP + CHUNK);        // CHUNK
        const int cb = blockIdx.x * CHUNK;
        if (t < NBUCK_MAX) cnt[t] = 0;
        __syncthreads();

        unsigned int ep[8]; int eb[8];
#pragma unroll
        for (int j = 0; j < 2; j++) {
            int idx4 = (cb >> 2) + j * 512 + t;
            int idx  = idx4 << 2;
            if (idx + 3 < e) {
                int4v s4 = __builtin_nontemporal_load(((const int4v*)src) + idx4);
                int4v d4 = __builtin_nontemporal_load(((const int4v*)dst) + idx4);
#pragma unroll
                for (int q = 0; q < 4; q++) {
                    ep[j*4+q] = ((unsigned int)s4[q] << BSHIFT) | (unsigned int)(d4[q] & (NPB-1));
                    eb[j*4+q] = d4[q] >> BSHIFT;
                    atomicAdd(&cnt[eb[j*4+q]], 1);
                }
            } else {
#pragma unroll
                for (int q = 0; q < 4; q++) {
                    int i = idx + q;
                    eb[j*4+q] = -1;
                    if (i < e) {
                        int s = src[i], d = dst[i];
                        ep[j*4+q] = ((unsigned int)s << BSHIFT) | (unsigned int)(d & (NPB-1));
                        eb[j*4+q] = d >> BSHIFT;
                        atomicAdd(&cnt[eb[j*4+q]], 1);
                    }
                }
            }
        }
        __syncthreads();
        if (t < NBUCK_MAX) offs[t] = cnt[t];
        __syncthreads();
        for (int off = 1; off < NBUCK_MAX; off <<= 1) {
            int u = 0;
            if (t < NBUCK_MAX && t >= off) u = offs[t - off];
            __syncthreads();
            if (t < NBUCK_MAX) offs[t] += u;
            __syncthreads();
        }
        if (t < NBUCK_MAX) {
            int ex = offs[t] - cnt[t];
            offs[t] = ex;
            cur[t] = ex;
            if (cnt[t] > 0) base[t] = atomicAdd(&bcur[t], cnt[t]);
        }
        __syncthreads();
#pragma unroll
        for (int j = 0; j < 8; j++) {
            if (eb[j] >= 0) {
                int pos = atomicAdd(&cur[eb[j]], 1);
                sP[pos] = ep[j];
                sB[pos] = (unsigned char)eb[j];
            }
        }
        __syncthreads();
        int nv = min(CHUNK, e - cb);
        for (int i = t; i < nv; i += 512) {
            int b = sB[i];
            __builtin_nontemporal_store(sP[i], &pairs[(size_t)b * CAP + base[b] + (i - offs[b])]);
        }
    } else {
        // ---------------- gemm1 role (27.6KB LDS) ----------------
        short* Wl = (short*)smem;            // [64][72] (transposed W)
        short* Xl = Wl + 64 * 72;            // 2 halves x [64][72]
        const int tile = (int)blockIdx.x - pblocks;
        const int half = t >> 8;
        const int ht   = t & 255;
        const int rowBase = tile * 128 + half * 64;
        short* Xh = Xl + half * 64 * 72;

        for (int i = t; i < 4096; i += 512) {
            int k = i >> 6, nn = i & 63;
            Wl[nn * 72 + k] = (short)f2bf(W[i]);
        }
        for (int i = ht; i < 1024; i += 256) {
            int r = i >> 4, c4 = i & 15;
            int row = rowBase + r;
            float4v v = {0.f, 0.f, 0.f, 0.f};
            if (row < nrows) v = __builtin_nontemporal_load(((const float4v*)(X + (size_t)row * 64)) + c4);
            ushort4 pk = make_ushort4((unsigned short)f2bf(v[0]), (unsigned short)f2bf(v[1]),
                                      (unsigned short)f2bf(v[2]), (unsigned short)f2bf(v[3]));
            *(ushort4*)(Xh + r * 72 + c4 * 4) = pk;
        }
        __syncthreads();

        const int w = ht >> 6;           // wave within half -> 16-row stripe
        const int lane = t & 63;
        const int q = lane >> 4, mn = lane & 15;

        fragf acc0 = {0,0,0,0}, acc1 = {0,0,0,0}, acc2 = {0,0,0,0}, acc3 = {0,0,0,0};
#pragma unroll
        for (int kk = 0; kk < 2; kk++) {
            frag16 a  = *(const frag16*)(Xh + (w * 16 + mn) * 72 + kk * 32 + q * 8);
            frag16 b0 = *(const frag16*)(Wl + ( 0 + mn) * 72 + kk * 32 + q * 8);
            frag16 b1 = *(const frag16*)(Wl + (16 + mn) * 72 + kk * 32 + q * 8);
            frag16 b2 = *(const frag16*)(Wl + (32 + mn) * 72 + kk * 32 + q * 8);
            frag16 b3 = *(const frag16*)(Wl + (48 + mn) * 72 + kk * 32 + q * 8);
            acc0 = __builtin_amdgcn_mfma_f32_16x16x32_bf16(a, b0, acc0, 0, 0, 0);
            acc1 = __builtin_amdgcn_mfma_f32_16x16x32_bf16(a, b1, acc1, 0, 0, 0);
            acc2 = __builtin_amdgcn_mfma_f32_16x16x32_bf16(a, b2, acc2, 0, 0, 0);
            acc3 = __builtin_amdgcn_mfma_f32_16x16x32_bf16(a, b3, acc3, 0, 0, 0);
        }
#pragma unroll
        for (int reg = 0; reg < 4; reg++) {
            int rl = w * 16 + q * 4 + reg;
            int row = rowBase + rl;
            if (row < nrows) {
                size_t ro = (size_t)row * 64;
                Y16[ro +  0 + mn] = (unsigned short)f2bf(acc0[reg]);
                Y16[ro + 16 + mn] = (unsigned short)f2bf(acc1[reg]);
                Y16[ro + 32 + mn] = (unsigned short)f2bf(acc2[reg]);
                Y16[ro + 48 + mn] = (unsigned short)f2bf(acc3[reg]);
            }
        }
    }
}

// ---- per-bucket counting sort (slab in LDS, 1024 threads/block) ----
// Emits srcs (slab layout), meta = (beg,end,dinv) per node, dinv array.
__global__ __launch_bounds__(1024) void bucket_csr(const unsigned int* __restrict__ pairs,
                                                   const int* __restrict__ bcur,
                                                   float4* __restrict__ meta,
                                                   float* __restrict__ dinv,
                                                   int* __restrict__ srcs,
                                                   int n) {
    __shared__ __align__(16) unsigned int sP[CAP];
    __shared__ int cnt[NPB];
    __shared__ int cur[NPB];
    __shared__ int tsum[NPB];
    const int b = blockIdx.x;
    const int t = threadIdx.x;
    const int nb = b << BSHIFT;
    const int nn = min(NPB, n - nb);
    const size_t slab = (size_t)b * CAP;
    const int cE = bcur[b];

    const int c4 = cE >> 2;
    const uint4v* p4 = (const uint4v*)(pairs + slab);
    for (int i = t; i < c4; i += 1024) {
        uint4v v = __builtin_nontemporal_load(p4 + i);
        ((uint4v*)sP)[i] = v;
    }
    for (int i = (c4 << 2) + t; i < cE; i += 1024) sP[i] = pairs[slab + i];
    if (t < NPB) cnt[t] = 0;
    __syncthreads();

    for (int i = t; i < cE; i += 1024)
        atomicAdd(&cnt[sP[i] & (NPB - 1)], 1);
    __syncthreads();

    int v = (t < NPB) ? cnt[t] : 0;
    if (t < NPB) tsum[t] = v;
    __syncthreads();
    for (int off = 1; off < NPB; off <<= 1) {
        int u = 0;
        if (t < NPB && t >= off) u = tsum[t - off];
        __syncthreads();
        if (t < NPB) tsum[t] += u;
        __syncthreads();
    }
    if (t < NPB) {
        int ex = tsum[t] - v;
        cur[t] = ex;
        if (t < nn) {
            int g = (int)slab + ex;
            float di = rsqrtf((float)v + 1.0f);
            meta[nb + t] = make_float4(__int_as_float(g), __int_as_float(g + v), di, 0.f);
            dinv[nb + t] = di;
        }
    }
    __syncthreads();
    for (int i = t; i < cE; i += 1024) {
        unsigned int p = sP[i];
        int pos = atomicAdd(&cur[p & (NPB - 1)], 1);
        __builtin_nontemporal_store((int)(p >> BSHIFT), &srcs[slab + pos]);
    }
}

// ---- Y16[N,64](bf16) = (X @ W) * dinv[row], via 16x16x32 bf16 MFMA ----
// (standalone form, used for layer 2; input bf16, pre-scales by dinv)
template<bool XF32>
__global__ __launch_bounds__(256) void gemm_mfma(const void* __restrict__ Xin,
                                                 const float* __restrict__ W,
                                                 const float* __restrict__ dinv,
                                                 unsigned short* __restrict__ Y16,
                                                 int nrows) {
    __shared__ __align__(16) short Xl[64 * 72];
    __shared__ __align__(16) short Wl[64 * 72];   // Wl[n][k] (transposed)
    __shared__ float dl[64];
    const int tid = threadIdx.x;
    const int rowBase = blockIdx.x * 64;

    for (int i = tid; i < 4096; i += 256) {
        int k = i >> 6, nn = i & 63;
        Wl[nn * 72 + k] = (short)f2bf(W[i]);
    }
    if (XF32) {
        const float* X = (const float*)Xin;
        for (int i = tid; i < 1024; i += 256) {
            int r = i >> 4, c4 = i & 15;
            int row = rowBase + r;
            float4v v = {0.f, 0.f, 0.f, 0.f};
            if (row < nrows) v = __builtin_nontemporal_load(((const float4v*)(X + (size_t)row * 64)) + c4);
            ushort4 pk = make_ushort4((unsigned short)f2bf(v[0]), (unsigned short)f2bf(v[1]),
                                      (unsigned short)f2bf(v[2]), (unsigned short)f2bf(v[3]));
            *(ushort4*)(Xl + r * 72 + c4 * 4) = pk;
        }
    } else {
        const unsigned short* X = (const unsigned short*)Xin;
        for (int i = tid; i < 512; i += 256) {
            int r = i >> 3, c8 = i & 7;
            int row = rowBase + r;
            uint4v v = {0, 0, 0, 0};
            if (row < nrows) v = __builtin_nontemporal_load(((const uint4v*)(X + (size_t)row * 64)) + c8);
            *(uint4v*)(Xl + r * 72 + c8 * 8) = v;
        }
    }
    if (tid < 64) {
        int row = rowBase + tid;
        dl[tid] = (row < nrows) ? dinv[row] : 0.f;
    }
    __syncthreads();

    const int w = tid >> 6;          // wave id -> 16-row stripe
    const int lane = tid & 63;
    const int q = lane >> 4, mn = lane & 15;

    fragf acc0 = {0,0,0,0}, acc1 = {0,0,0,0}, acc2 = {0,0,0,0}, acc3 = {0,0,0,0};
#pragma unroll
    for (int kk = 0; kk < 2; kk++) {
        frag16 a  = *(const frag16*)(Xl + (w * 16 + mn) * 72 + kk * 32 + q * 8);
        frag16 b0 = *(const frag16*)(Wl + ( 0 + mn) * 72 + kk * 32 + q * 8);
        frag16 b1 = *(const frag16*)(Wl + (16 + mn) * 72 + kk * 32 + q * 8);
        frag16 b2 = *(const frag16*)(Wl + (32 + mn) * 72 + kk * 32 + q * 8);
        frag16 b3 = *(const frag16*)(Wl + (48 + mn) * 72 + kk * 32 + q * 8);
        acc0 = __builtin_amdgcn_mfma_f32_16x16x32_bf16(a, b0, acc0, 0, 0, 0);
        acc1 = __builtin_amdgcn_mfma_f32_16x16x32_bf16(a, b1, acc1, 0, 0, 0);
        acc2 = __builtin_amdgcn_mfma_f32_16x16x32_bf16(a, b2, acc2, 0, 0, 0);
        acc3 = __builtin_amdgcn_mfma_f32_16x16x32_bf16(a, b3, acc3, 0, 0, 0);
    }
#pragma unroll
    for (int reg = 0; reg < 4; reg++) {
        int rl = w * 16 + q * 4 + reg;
        int row = rowBase + rl;
        if (row < nrows) {
            float di = dl[rl];
            size_t ro = (size_t)row * 64;
            Y16[ro +  0 + mn] = (unsigned short)f2bf(acc0[reg] * di);
            Y16[ro + 16 + mn] = (unsigned short)f2bf(acc1[reg] * di);
            Y16[ro + 32 + mn] = (unsigned short)f2bf(acc2[reg] * di);
            Y16[ro + 48 + mn] = (unsigned short)f2bf(acc3[reg] * di);
        }
    }
}

// ---- gather: 2 nodes/wave, 8-deep MLP, broadcast row loads ----
// PRESCALED: rows already carry dinv[src] (layer 2).  Else fmaf with
// dinv[src] per edge (dinv is 400KB, L2-resident; same VALU cost as add).
// OUT16: write bf16 (layer 1, feeds gemm_mfma<false>); else fp32 (output).
template<bool OUT16, bool PRESCALED>
__global__ __launch_bounds__(256) void gather_nodes(const unsigned short* __restrict__ XW,
                                                    const float4* __restrict__ meta,
                                                    const int* __restrict__ srcs,
                                                    const float* __restrict__ dinv,
                                                    const float* __restrict__ bias,
                                                    void* __restrict__ outp, int n) {
    int wv   = (blockIdx.x * 256 + threadIdx.x) >> 6;
    int lane = threadIdx.x & 63;
    int node = wv * 2 + (lane >> 5);
    int fl   = lane & 31;                  // feature pair: 2*fl, 2*fl+1
    if (node >= n) return;
    const unsigned int* Xp = (const unsigned int*)XW;   // [N][32] bf16x2
    float4 mv = meta[node];
    int beg = __float_as_int(mv.x), end = __float_as_int(mv.y);
    float di = mv.z;
    float2 bv = *(const float2*)(bias + fl * 2);
    unsigned int sv = Xp[(size_t)node * 32 + fl];
    float acc0, acc1;                      // self-loop term
    if (PRESCALED) { acc0 = bfl(sv);      acc1 = bfh(sv); }
    else           { acc0 = bfl(sv) * di; acc1 = bfh(sv) * di; }

    int e = beg;
    for (; e + 8 <= end; e += 8) {
        int s0 = __builtin_nontemporal_load(srcs + e);
        int s1 = __builtin_nontemporal_load(srcs + e + 1);
        int s2 = __builtin_nontemporal_load(srcs + e + 2);
        int s3 = __builtin_nontemporal_load(srcs + e + 3);
        int s4 = __builtin_nontemporal_load(srcs + e + 4);
        int s5 = __builtin_nontemporal_load(srcs + e + 5);
        int s6 = __builtin_nontemporal_load(srcs + e + 6);
        int s7 = __builtin_nontemporal_load(srcs + e + 7);
        unsigned int v0 = Xp[(size_t)s0 * 32 + fl];
        unsigned int v1 = Xp[(size_t)s1 * 32 + fl];
        unsigned int v2 = Xp[(size_t)s2 * 32 + fl];
        unsigned int v3 = Xp[(size_t)s3 * 32 + fl];
        unsigned int v4 = Xp[(size_t)s4 * 32 + fl];
        unsigned int v5 = Xp[(size_t)s5 * 32 + fl];
        unsigned int v6 = Xp[(size_t)s6 * 32 + fl];
        unsigned int v7 = Xp[(size_t)s7 * 32 + fl];
        if (PRESCALED) {
            acc0 += bfl(v0); acc1 += bfh(v0);
            acc0 += bfl(v1); acc1 += bfh(v1);
            acc0 += bfl(v2); acc1 += bfh(v2);
            acc0 += bfl(v3); acc1 += bfh(v3);
            acc0 += bfl(v4); acc1 += bfh(v4);
            acc0 += bfl(v5); acc1 += bfh(v5);
            acc0 += bfl(v6); acc1 += bfh(v6);
            acc0 += bfl(v7); acc1 += bfh(v7);
        } else {
            float d0 = dinv[s0], d1 = dinv[s1], d2 = dinv[s2], d3 = dinv[s3];
            float d4 = dinv[s4], d5 = dinv[s5], d6 = dinv[s6], d7 = dinv[s7];
            acc0 = fmaf(bfl(v0), d0, acc0); acc1 = fmaf(bfh(v0), d0, acc1);
            acc0 = fmaf(bfl(v1), d1, acc0); acc1 = fmaf(bfh(v1), d1, acc1);
            acc0 = fmaf(bfl(v2), d2, acc0); acc1 = fmaf(bfh(v2), d2, acc1);
            acc0 = fmaf(bfl(v3), d3, acc0); acc1 = fmaf(bfh(v3), d3, acc1);
            acc0 = fmaf(bfl(v4), d4, acc0); acc1 = fmaf(bfh(v4), d4, acc1);
            acc0 = fmaf(bfl(v5), d5, acc0); acc1 = fmaf(bfh(v5), d5, acc1);
            acc0 = fmaf(bfl(v6), d6, acc0); acc1 = fmaf(bfh(v6), d6, acc1);
            acc0 = fmaf(bfl(v7), d7, acc0); acc1 = fmaf(bfh(v7), d7, acc1);
        }
    }
    for (; e < end; e++) {
        int s = __builtin_nontemporal_load(srcs + e);
        unsigned int v = Xp[(size_t)s * 32 + fl];
        if (PRESCALED) {
            acc0 += bfl(v); acc1 += bfh(v);
        } else {
            float dsv = dinv[s];
            acc0 = fmaf(bfl(v), dsv, acc0); acc1 = fmaf(bfh(v), dsv, acc1);
        }
    }
    float r0 = fmaxf(acc0 * di + bv.x, 0.f);
    float r1 = fmaxf(acc1 * di + bv.y, 0.f);
    if (OUT16) {
        unsigned int pk = f2bf(r0) | (f2bf(r1) << 16);
        __builtin_nontemporal_store(pk, (unsigned int*)outp + (size_t)node * 32 + fl);
    } else {
        float* op = (float*)outp + (size_t)node * 64 + fl * 2;
        __builtin_nontemporal_store(r0, op);
        __builtin_nontemporal_store(r1, op + 1);
    }
}

extern "C" void kernel_launch(void* const* d_in, const int* in_sizes, int n_in,
                              void* d_out, int out_size, void* d_ws, size_t ws_size,
                              hipStream_t stream) {
    const float* x  = (const float*)d_in[0];
    const int*   ei = (const int*)d_in[1];
    const float* W1 = (const float*)d_in[2];
    const float* b1 = (const float*)d_in[3];
    const float* W2 = (const float*)d_in[4];
    const float* b2 = (const float*)d_in[5];
    float* out = (float*)d_out;

    const int N = in_sizes[0] / 64;
    const int E = in_sizes[1] / 2;
    const int* srcA = ei;
    const int* dstA = ei + E;
    const int K = (N + NPB - 1) >> BSHIFT;   // 196

    char* ws = (char*)d_ws;
    auto alloc = [&](size_t bytes) { char* p = ws; ws += (bytes + 255) & ~(size_t)255; return p; };
    unsigned short* A16 = (unsigned short*)alloc((size_t)N * 64 * 2);  // XW bf16
    unsigned short* B16 = (unsigned short*)alloc((size_t)N * 64 * 2);  // h1 bf16
    float*  dinv  = (float*) alloc((size_t)N * 4);
    float4* meta  = (float4*)alloc((size_t)N * 16);
    int*   srcs_sorted = (int*)alloc((size_t)K * CAP * 4);             // slab layout
    unsigned int* pairs = (unsigned int*)alloc((size_t)K * CAP * 4);   // own buffer (gemm1 runs concurrently)
    int*   bcur   = (int*)  alloc(NBUCK_MAX * 4);

    const int pblocks = (E + CHUNK - 1) / CHUNK;     // 391
    const int gblocks = (N + 127) / 128;             // 782
    const int nodeBlocks = (N + 7) / 8;              // 4 waves/block x 2 nodes/wave

    // ---- CSR build || layer-1 gemm (fused; gemm1 output unscaled) ----
    hipMemsetAsync(bcur, 0, NBUCK_MAX * 4, stream);
    fused_build_gemm1<<<pblocks + gblocks, 512, 0, stream>>>(srcA, dstA, bcur, pairs, E,
                                                             pblocks, x, W1, A16, N);
    bucket_csr<<<K, 1024, 0, stream>>>(pairs, bcur, meta, dinv, srcs_sorted, N);

    // ---- layer 1 gather (applies dinv[src] per edge via fmaf) ----
    gather_nodes<true, false><<<nodeBlocks, 256, 0, stream>>>(A16, meta, srcs_sorted,
                                                              dinv, b1, B16, N);
    // ---- layer 2 ----
    gemm_mfma<false><<<(N + 63) / 64, 256, 0, stream>>>(B16, W2, dinv, A16, N);
    gather_nodes<false, true><<<nodeBlocks, 256, 0, stream>>>(A16, meta, srcs_sorted,
                                                              dinv, b2, out, N);
}

// Round 3
// 223.231 us; speedup vs baseline: 1.1616x; 1.1616x over previous
//
#include <hip/hip_runtime.h>

// GCN 2-layer, N=100000, E=1600000, dim 64, fp32 in/out.
// R3: NT reverted everywhere except full-line single-use streams (edge
// list loads, X fp32 loads, final out store).  R2 showed NT scatter
// stores cause line-granular write amplification (srcs: 12->133MB HBM
// writes) and NT sequential srcs loads defeat the 16x line reuse.
// Structure: fused(partition || gemm1-unscaled) -> bucket_csr (count
// sort + A16 *= dinv[row] tail) -> fused(gather1 + h1@W2 MFMA -> C16
// scaled) -> gather2 -> out fp32.  B16 buffer and standalone gemm2
// eliminated.  Gather remains MSHR/L2-random-service bound (~85MB row
// misses per pass); bf16 rows are the byte floor at the 9.8e-3 absmax.

#define BSHIFT 9             // bucket = dst >> 9  (512 nodes per bucket)
#define NPB 512              // nodes per bucket
#define NBUCK_MAX 256        // K = ceil(100000/512) = 196
#define CAP 10240            // slab capacity; E[edges/bucket]=8192, sd~90
#define CHUNK 4096

using frag16 = __attribute__((ext_vector_type(8))) short;   // 8 bf16
using fragf  = __attribute__((ext_vector_type(4))) float;   // 4 fp32 acc
typedef int          int4v   __attribute__((ext_vector_type(4)));
typedef unsigned int uint4v  __attribute__((ext_vector_type(4)));
typedef float        float4v __attribute__((ext_vector_type(4)));

__device__ __forceinline__ unsigned int f2bf(float f) {   // RNE fp32->bf16
    unsigned int u = __float_as_uint(f);
    return (u + 0x7fffu + ((u >> 16) & 1u)) >> 16;
}
__device__ __forceinline__ float bfl(unsigned int u) { return __uint_as_float(u << 16); }
__device__ __forceinline__ float bfh(unsigned int u) { return __uint_as_float(u & 0xffff0000u); }

// ---- fused: edge partition (blocks [0,pblocks)) + X@W1 bf16 gemm ----
// Partition: pack = (src << 9) | (dst & 511) into per-bucket slabs.
// Gemm role: 512 thr = two 64-row tiles; output UNSCALED bf16 (dinv
// applied by bucket_csr's scale tail, so no csr->gemm1 dependency).
__global__ __launch_bounds__(512) void fused_build_gemm1(
        const int* __restrict__ src, const int* __restrict__ dst,
        int* __restrict__ bcur, unsigned int* __restrict__ pairs, int e, int pblocks,
        const float* __restrict__ X, const float* __restrict__ W,
        unsigned short* __restrict__ Y16, int nrows) {
    __shared__ __align__(16) char smem[28672];
    const int t = threadIdx.x;

    if ((int)blockIdx.x < pblocks) {
        // ---------------- partition role (24.5KB LDS) ----------------
        int* cnt  = (int*)smem;
        int* offs = cnt + NBUCK_MAX;
        int* cur  = offs + NBUCK_MAX;
        int* base = cur + NBUCK_MAX;
        unsigned int*  sP = (unsigned int*)(base + NBUCK_MAX);   // CHUNK
        unsigned char* sB = (unsigned char*)(sP + CHUNK);        // CHUNK
        const int cb = blockIdx.x * CHUNK;
        if (t < NBUCK_MAX) cnt[t] = 0;
        __syncthreads();

        unsigned int ep[8]; int eb[8];
#pragma unroll
        for (int j = 0; j < 2; j++) {
            int idx4 = (cb >> 2) + j * 512 + t;
            int idx  = idx4 << 2;
            if (idx + 3 < e) {
                int4v s4 = __builtin_nontemporal_load(((const int4v*)src) + idx4);
                int4v d4 = __builtin_nontemporal_load(((const int4v*)dst) + idx4);
#pragma unroll
                for (int q = 0; q < 4; q++) {
                    ep[j*4+q] = ((unsigned int)s4[q] << BSHIFT) | (unsigned int)(d4[q] & (NPB-1));
                    eb[j*4+q] = d4[q] >> BSHIFT;
                    atomicAdd(&cnt[eb[j*4+q]], 1);
                }
            } else {
#pragma unroll
                for (int q = 0; q < 4; q++) {
                    int i = idx + q;
                    eb[j*4+q] = -1;
                    if (i < e) {
                        int s = src[i], d = dst[i];
                        ep[j*4+q] = ((unsigned int)s << BSHIFT) | (unsigned int)(d & (NPB-1));
                        eb[j*4+q] = d >> BSHIFT;
                        atomicAdd(&cnt[eb[j*4+q]], 1);
                    }
                }
            }
        }
        __syncthreads();
        if (t < NBUCK_MAX) offs[t] = cnt[t];
        __syncthreads();
        for (int off = 1; off < NBUCK_MAX; off <<= 1) {
            int u = 0;
            if (t < NBUCK_MAX && t >= off) u = offs[t - off];
            __syncthreads();
            if (t < NBUCK_MAX) offs[t] += u;
            __syncthreads();
        }
        if (t < NBUCK_MAX) {
            int ex = offs[t] - cnt[t];
            offs[t] = ex;
            cur[t] = ex;
            if (cnt[t] > 0) base[t] = atomicAdd(&bcur[t], cnt[t]);
        }
        __syncthreads();
#pragma unroll
        for (int j = 0; j < 8; j++) {
            if (eb[j] >= 0) {
                int pos = atomicAdd(&cur[eb[j]], 1);
                sP[pos] = ep[j];
                sB[pos] = (unsigned char)eb[j];
            }
        }
        __syncthreads();
        int nv = min(CHUNK, e - cb);
        for (int i = t; i < nv; i += 512) {
            int b = sB[i];
            pairs[(size_t)b * CAP + base[b] + (i - offs[b])] = sP[i];   // plain store
        }
    } else {
        // ---------------- gemm1 role (27.6KB LDS) ----------------
        short* Wl = (short*)smem;            // [64][72] (transposed W)
        short* Xl = Wl + 64 * 72;            // 2 halves x [64][72]
        const int tile = (int)blockIdx.x - pblocks;
        const int half = t >> 8;
        const int ht   = t & 255;
        const int rowBase = tile * 128 + half * 64;
        short* Xh = Xl + half * 64 * 72;

        for (int i = t; i < 4096; i += 512) {
            int k = i >> 6, nn = i & 63;
            Wl[nn * 72 + k] = (short)f2bf(W[i]);
        }
        for (int i = ht; i < 1024; i += 256) {
            int r = i >> 4, c4 = i & 15;
            int row = rowBase + r;
            float4v v = {0.f, 0.f, 0.f, 0.f};
            if (row < nrows) v = __builtin_nontemporal_load(((const float4v*)(X + (size_t)row * 64)) + c4);
            ushort4 pk = make_ushort4((unsigned short)f2bf(v[0]), (unsigned short)f2bf(v[1]),
                                      (unsigned short)f2bf(v[2]), (unsigned short)f2bf(v[3]));
            *(ushort4*)(Xh + r * 72 + c4 * 4) = pk;
        }
        __syncthreads();

        const int w = ht >> 6;           // wave within half -> 16-row stripe
        const int lane = t & 63;
        const int q = lane >> 4, mn = lane & 15;

        fragf acc0 = {0,0,0,0}, acc1 = {0,0,0,0}, acc2 = {0,0,0,0}, acc3 = {0,0,0,0};
#pragma unroll
        for (int kk = 0; kk < 2; kk++) {
            frag16 a  = *(const frag16*)(Xh + (w * 16 + mn) * 72 + kk * 32 + q * 8);
            frag16 b0 = *(const frag16*)(Wl + ( 0 + mn) * 72 + kk * 32 + q * 8);
            frag16 b1 = *(const frag16*)(Wl + (16 + mn) * 72 + kk * 32 + q * 8);
            frag16 b2 = *(const frag16*)(Wl + (32 + mn) * 72 + kk * 32 + q * 8);
            frag16 b3 = *(const frag16*)(Wl + (48 + mn) * 72 + kk * 32 + q * 8);
            acc0 = __builtin_amdgcn_mfma_f32_16x16x32_bf16(a, b0, acc0, 0, 0, 0);
            acc1 = __builtin_amdgcn_mfma_f32_16x16x32_bf16(a, b1, acc1, 0, 0, 0);
            acc2 = __builtin_amdgcn_mfma_f32_16x16x32_bf16(a, b2, acc2, 0, 0, 0);
            acc3 = __builtin_amdgcn_mfma_f32_16x16x32_bf16(a, b3, acc3, 0, 0, 0);
        }
#pragma unroll
        for (int reg = 0; reg < 4; reg++) {
            int rl = w * 16 + q * 4 + reg;
            int row = rowBase + rl;
            if (row < nrows) {
                size_t ro = (size_t)row * 64;
                Y16[ro +  0 + mn] = (unsigned short)f2bf(acc0[reg]);
                Y16[ro + 16 + mn] = (unsigned short)f2bf(acc1[reg]);
                Y16[ro + 32 + mn] = (unsigned short)f2bf(acc2[reg]);
                Y16[ro + 48 + mn] = (unsigned short)f2bf(acc3[reg]);
            }
        }
    }
}

// ---- per-bucket counting sort + A16 row scale (1024 threads/block) ----
// Emits srcs (slab layout), meta = (beg,end,dinv); then scales this
// bucket's A16 rows by dinv (coalesced, block-local).
__global__ __launch_bounds__(1024) void bucket_csr(const unsigned int* __restrict__ pairs,
                                                   const int* __restrict__ bcur,
                                                   float4* __restrict__ meta,
                                                   int* __restrict__ srcs,
                                                   unsigned int* __restrict__ A,  // [N][32] bf16x2
                                                   int n) {
    __shared__ __align__(16) unsigned int sP[CAP];
    __shared__ int cnt[NPB];
    __shared__ int cur[NPB];
    __shared__ int tsum[NPB];
    __shared__ float dL[NPB];
    const int b = blockIdx.x;
    const int t = threadIdx.x;
    const int nb = b << BSHIFT;
    const int nn = min(NPB, n - nb);
    const size_t slab = (size_t)b * CAP;
    const int cE = bcur[b];

    const int c4 = cE >> 2;
    const uint4v* p4 = (const uint4v*)(pairs + slab);
    for (int i = t; i < c4; i += 1024) ((uint4v*)sP)[i] = p4[i];
    for (int i = (c4 << 2) + t; i < cE; i += 1024) sP[i] = pairs[slab + i];
    if (t < NPB) cnt[t] = 0;
    __syncthreads();

    for (int i = t; i < cE; i += 1024)
        atomicAdd(&cnt[sP[i] & (NPB - 1)], 1);
    __syncthreads();

    int v = (t < NPB) ? cnt[t] : 0;
    if (t < NPB) tsum[t] = v;
    __syncthreads();
    for (int off = 1; off < NPB; off <<= 1) {
        int u = 0;
        if (t < NPB && t >= off) u = tsum[t - off];
        __syncthreads();
        if (t < NPB) tsum[t] += u;
        __syncthreads();
    }
    if (t < NPB) {
        int ex = tsum[t] - v;
        cur[t] = ex;
        float di = rsqrtf((float)v + 1.0f);
        dL[t] = di;
        if (t < nn) {
            int g = (int)slab + ex;
            meta[nb + t] = make_float4(__int_as_float(g), __int_as_float(g + v), di, 0.f);
        }
    }
    __syncthreads();
    for (int i = t; i < cE; i += 1024) {
        unsigned int p = sP[i];
        int pos = atomicAdd(&cur[p & (NPB - 1)], 1);
        srcs[slab + pos] = (int)(p >> BSHIFT);                  // plain store
    }
    // ---- scale tail: A16 rows of this bucket *= dinv[row] ----
    const int tot = nn << 5;                                    // nn * 32 dwords
    for (int i = t; i < tot; i += 1024) {
        int r = i >> 5, c = i & 31;
        size_t idx = ((size_t)(nb + r) << 5) + c;
        unsigned int u = A[idx];
        float d = dL[r];
        A[idx] = f2bf(bfl(u) * d) | (f2bf(bfh(u) * d) << 16);
    }
}

// ---- fused gather-1 + h1@W2 MFMA -> C16 (dinv-scaled), 1024 thr ----
// 16 waves x 2 nodes = 32 consecutive nodes/block.  Gather identical to
// the proven 2-node/wave form (prescaled rows, plain loads).  h1 bf16
// staged in LDS; waves 0-7 run the 32x64 @ 64x64 MFMA (8 tiles x 2 MFMA).
__global__ __launch_bounds__(1024) void fused_g1_gemm2(
        const unsigned short* __restrict__ XW,      // A16, prescaled
        const float4* __restrict__ meta,
        const int* __restrict__ srcs,
        const float* __restrict__ b1,
        const float* __restrict__ W2,
        unsigned short* __restrict__ C16, int n) {
    __shared__ __align__(16) short Wl[64 * 72];   // W2 transposed bf16
    __shared__ __align__(16) short Xl[32 * 72];   // h1 rows bf16
    __shared__ float dl[32];
    const int t = threadIdx.x;
    const int lane = t & 63;
    const int wv = t >> 6;                        // 0..15
    const int nbase = blockIdx.x * 32;
    const int local = wv * 2 + (lane >> 5);
    const int node = nbase + local;
    const int fl = lane & 31;                     // feature pair 2*fl, 2*fl+1
    const bool active = node < n;

    for (int i = t; i < 4096; i += 1024) {
        int k = i >> 6, nn2 = i & 63;
        Wl[nn2 * 72 + k] = (short)f2bf(W2[i]);
    }

    float r0 = 0.f, r1 = 0.f, di = 0.f;
    if (active) {
        const unsigned int* Xp = (const unsigned int*)XW;   // [N][32] bf16x2
        float4 mv = meta[node];
        int beg = __float_as_int(mv.x), end = __float_as_int(mv.y);
        di = mv.z;
        float2 bv = *(const float2*)(b1 + fl * 2);
        unsigned int sv = Xp[(size_t)node * 32 + fl];
        float acc0 = bfl(sv), acc1 = bfh(sv);               // self-loop

        int e = beg;
        for (; e + 8 <= end; e += 8) {
            int s0 = srcs[e],     s1 = srcs[e + 1], s2 = srcs[e + 2], s3 = srcs[e + 3];
            int s4 = srcs[e + 4], s5 = srcs[e + 5], s6 = srcs[e + 6], s7 = srcs[e + 7];
            unsigned int v0 = Xp[(size_t)s0 * 32 + fl];
            unsigned int v1 = Xp[(size_t)s1 * 32 + fl];
            unsigned int v2 = Xp[(size_t)s2 * 32 + fl];
            unsigned int v3 = Xp[(size_t)s3 * 32 + fl];
            unsigned int v4 = Xp[(size_t)s4 * 32 + fl];
            unsigned int v5 = Xp[(size_t)s5 * 32 + fl];
            unsigned int v6 = Xp[(size_t)s6 * 32 + fl];
            unsigned int v7 = Xp[(size_t)s7 * 32 + fl];
            acc0 += bfl(v0); acc1 += bfh(v0);
            acc0 += bfl(v1); acc1 += bfh(v1);
            acc0 += bfl(v2); acc1 += bfh(v2);
            acc0 += bfl(v3); acc1 += bfh(v3);
            acc0 += bfl(v4); acc1 += bfh(v4);
            acc0 += bfl(v5); acc1 += bfh(v5);
            acc0 += bfl(v6); acc1 += bfh(v6);
            acc0 += bfl(v7); acc1 += bfh(v7);
        }
        for (; e < end; e++) {
            int s = srcs[e];
            unsigned int vv = Xp[(size_t)s * 32 + fl];
            acc0 += bfl(vv); acc1 += bfh(vv);
        }
        r0 = fmaxf(acc0 * di + bv.x, 0.f);
        r1 = fmaxf(acc1 * di + bv.y, 0.f);
    }
    *(unsigned int*)(Xl + local * 72 + fl * 2) = f2bf(r0) | (f2bf(r1) << 16);
    if ((lane & 31) == 0) dl[local] = di;
    __syncthreads();

    // ---- 32x64 = (32x64 h1) @ (64x64 W2), 8 tiles on waves 0..7 ----
    if (wv < 8) {
        const int stripe = wv >> 2;      // row stripe 0/1
        const int cb = wv & 3;           // col block 0..3
        const int q = lane >> 4, mn = lane & 15;
        fragf acc = {0, 0, 0, 0};
#pragma unroll
        for (int kk = 0; kk < 2; kk++) {
            frag16 a = *(const frag16*)(Xl + (stripe * 16 + mn) * 72 + kk * 32 + q * 8);
            frag16 bb = *(const frag16*)(Wl + (cb * 16 + mn) * 72 + kk * 32 + q * 8);
            acc = __builtin_amdgcn_mfma_f32_16x16x32_bf16(a, bb, acc, 0, 0, 0);
        }
#pragma unroll
        for (int reg = 0; reg < 4; reg++) {
            int row = stripe * 16 + q * 4 + reg;
            int nd = nbase + row;
            if (nd < n) {
                C16[(size_t)nd * 64 + cb * 16 + mn] = (unsigned short)f2bf(acc[reg] * dl[row]);
            }
        }
    }
}

// ---- gather-2: 2 nodes/wave, prescaled rows, fp32 NT out ----
__global__ __launch_bounds__(256) void gather_out(const unsigned short* __restrict__ XW,
                                                  const float4* __restrict__ meta,
                                                  const int* __restrict__ srcs,
                                                  const float* __restrict__ bias,
                                                  float* __restrict__ outp, int n) {
    int wv   = (blockIdx.x * 256 + threadIdx.x) >> 6;
    int lane = threadIdx.x & 63;
    int node = wv * 2 + (lane >> 5);
    int fl   = lane & 31;                  // feature pair: 2*fl, 2*fl+1
    if (node >= n) return;
    const unsigned int* Xp = (const unsigned int*)XW;   // [N][32] bf16x2
    float4 mv = meta[node];
    int beg = __float_as_int(mv.x), end = __float_as_int(mv.y);
    float di = mv.z;
    float2 bv = *(const float2*)(bias + fl * 2);
    unsigned int sv = Xp[(size_t)node * 32 + fl];
    float acc0 = bfl(sv), acc1 = bfh(sv);  // self-loop (row carries dinv)

    int e = beg;
    for (; e + 8 <= end; e += 8) {
        int s0 = srcs[e],     s1 = srcs[e + 1], s2 = srcs[e + 2], s3 = srcs[e + 3];
        int s4 = srcs[e + 4], s5 = srcs[e + 5], s6 = srcs[e + 6], s7 = srcs[e + 7];
        unsigned int v0 = Xp[(size_t)s0 * 32 + fl];
        unsigned int v1 = Xp[(size_t)s1 * 32 + fl];
        unsigned int v2 = Xp[(size_t)s2 * 32 + fl];
        unsigned int v3 = Xp[(size_t)s3 * 32 + fl];
        unsigned int v4 = Xp[(size_t)s4 * 32 + fl];
        unsigned int v5 = Xp[(size_t)s5 * 32 + fl];
        unsigned int v6 = Xp[(size_t)s6 * 32 + fl];
        unsigned int v7 = Xp[(size_t)s7 * 32 + fl];
        acc0 += bfl(v0); acc1 += bfh(v0);
        acc0 += bfl(v1); acc1 += bfh(v1);
        acc0 += bfl(v2); acc1 += bfh(v2);
        acc0 += bfl(v3); acc1 += bfh(v3);
        acc0 += bfl(v4); acc1 += bfh(v4);
        acc0 += bfl(v5); acc1 += bfh(v5);
        acc0 += bfl(v6); acc1 += bfh(v6);
        acc0 += bfl(v7); acc1 += bfh(v7);
    }
    for (; e < end; e++) {
        int s = srcs[e];
        unsigned int v = Xp[(size_t)s * 32 + fl];
        acc0 += bfl(v); acc1 += bfh(v);
    }
    float r0 = fmaxf(acc0 * di + bv.x, 0.f);
    float r1 = fmaxf(acc1 * di + bv.y, 0.f);
    // coalesced full-line single-use stream -> NT ok
    float* op = outp + (size_t)node * 64 + fl * 2;
    __builtin_nontemporal_store(r0, op);
    __builtin_nontemporal_store(r1, op + 1);
}

extern "C" void kernel_launch(void* const* d_in, const int* in_sizes, int n_in,
                              void* d_out, int out_size, void* d_ws, size_t ws_size,
                              hipStream_t stream) {
    const float* x  = (const float*)d_in[0];
    const int*   ei = (const int*)d_in[1];
    const float* W1 = (const float*)d_in[2];
    const float* b1 = (const float*)d_in[3];
    const float* W2 = (const float*)d_in[4];
    const float* b2 = (const float*)d_in[5];
    float* out = (float*)d_out;

    const int N = in_sizes[0] / 64;
    const int E = in_sizes[1] / 2;
    const int* srcA = ei;
    const int* dstA = ei + E;
    const int K = (N + NPB - 1) >> BSHIFT;   // 196

    char* ws = (char*)d_ws;
    auto alloc = [&](size_t bytes) { char* p = ws; ws += (bytes + 255) & ~(size_t)255; return p; };
    unsigned short* A16 = (unsigned short*)alloc((size_t)N * 64 * 2);  // XW1 bf16 (scaled by csr)
    unsigned short* C16 = (unsigned short*)alloc((size_t)N * 64 * 2);  // (h1@W2)*dinv bf16
    float4* meta  = (float4*)alloc((size_t)N * 16);
    int*   srcs_sorted = (int*)alloc((size_t)K * CAP * 4);             // slab layout
    unsigned int* pairs = (unsigned int*)alloc((size_t)K * CAP * 4);   // own buffer (gemm1 concurrent)
    int*   bcur   = (int*)  alloc(NBUCK_MAX * 4);

    const int pblocks = (E + CHUNK - 1) / CHUNK;     // 391
    const int gblocks = (N + 127) / 128;             // 782
    const int fgBlocks = (N + 31) / 32;              // 3125 (gather1+gemm2)
    const int g2Blocks = (N + 7) / 8;                // 12500

    // ---- CSR build || layer-1 gemm (fused; gemm1 output unscaled) ----
    hipMemsetAsync(bcur, 0, NBUCK_MAX * 4, stream);
    fused_build_gemm1<<<pblocks + gblocks, 512, 0, stream>>>(srcA, dstA, bcur, pairs, E,
                                                             pblocks, x, W1, A16, N);
    // ---- counting sort + A16 *= dinv[row] ----
    bucket_csr<<<K, 1024, 0, stream>>>(pairs, bcur, meta, srcs_sorted,
                                       (unsigned int*)A16, N);
    // ---- gather-1 fused with h1@W2 (writes scaled C16) ----
    fused_g1_gemm2<<<fgBlocks, 1024, 0, stream>>>(A16, meta, srcs_sorted, b1, W2, C16, N);
    // ---- gather-2 -> fp32 out ----
    gather_out<<<g2Blocks, 256, 0, stream>>>(C16, meta, srcs_sorted, b2, out, N);
}

// Round 4
// 207.801 us; speedup vs baseline: 1.2479x; 1.0743x over previous
//
#include <hip/hip_runtime.h>

// GCN 2-layer, N=100000, E=1600000, dim 64, fp32 in/out.
// R4: de-fused gather1+gemm2 (R3: barrier after variance-heavy gather
// phase serializes on the max-degree straggler among 32 nodes, 36->59us;
// never barrier after a variance phase).  Keep R3's wins: fused
// (partition || gemm1-unscaled) fat kernel, bucket_csr counting sort +
// A16 *= dinv[row] scale tail, NT only on full-line single-use coalesced
// streams (edge loads, X fp32 loads, final fp32 out store) -- R2 showed
// NT scatter stores amplify writes 10x and NT sequential srcs loads
// defeat line reuse.  Gathers: proven 2-node/wave broadcast-row form,
// rows prescaled, independent waves (no block barrier).  Gather is
// MSHR/L2-random-service bound (~84MB misses/pass @ ~2.3TB/s); bf16
// rows are the byte floor at the 9.8e-3 absmax threshold.

#define BSHIFT 9             // bucket = dst >> 9  (512 nodes per bucket)
#define NPB 512              // nodes per bucket
#define NBUCK_MAX 256        // K = ceil(100000/512) = 196
#define CAP 10240            // slab capacity; E[edges/bucket]=8192, sd~90
#define CHUNK 4096

using frag16 = __attribute__((ext_vector_type(8))) short;   // 8 bf16
using fragf  = __attribute__((ext_vector_type(4))) float;   // 4 fp32 acc
typedef int          int4v   __attribute__((ext_vector_type(4)));
typedef unsigned int uint4v  __attribute__((ext_vector_type(4)));
typedef float        float4v __attribute__((ext_vector_type(4)));

__device__ __forceinline__ unsigned int f2bf(float f) {   // RNE fp32->bf16
    unsigned int u = __float_as_uint(f);
    return (u + 0x7fffu + ((u >> 16) & 1u)) >> 16;
}
__device__ __forceinline__ float bfl(unsigned int u) { return __uint_as_float(u << 16); }
__device__ __forceinline__ float bfh(unsigned int u) { return __uint_as_float(u & 0xffff0000u); }

// ---- fused: edge partition (blocks [0,pblocks)) + X@W1 bf16 gemm ----
// Partition: pack = (src << 9) | (dst & 511) into per-bucket slabs.
// Gemm role: 512 thr = two 64-row tiles; output UNSCALED bf16 (dinv
// applied by bucket_csr's scale tail, so no csr->gemm1 dependency).
__global__ __launch_bounds__(512) void fused_build_gemm1(
        const int* __restrict__ src, const int* __restrict__ dst,
        int* __restrict__ bcur, unsigned int* __restrict__ pairs, int e, int pblocks,
        const float* __restrict__ X, const float* __restrict__ W,
        unsigned short* __restrict__ Y16, int nrows) {
    __shared__ __align__(16) char smem[28672];
    const int t = threadIdx.x;

    if ((int)blockIdx.x < pblocks) {
        // ---------------- partition role (24.5KB LDS) ----------------
        int* cnt  = (int*)smem;
        int* offs = cnt + NBUCK_MAX;
        int* cur  = offs + NBUCK_MAX;
        int* base = cur + NBUCK_MAX;
        unsigned int*  sP = (unsigned int*)(base + NBUCK_MAX);   // CHUNK
        unsigned char* sB = (unsigned char*)(sP + CHUNK);        // CHUNK
        const int cb = blockIdx.x * CHUNK;
        if (t < NBUCK_MAX) cnt[t] = 0;
        __syncthreads();

        unsigned int ep[8]; int eb[8];
#pragma unroll
        for (int j = 0; j < 2; j++) {
            int idx4 = (cb >> 2) + j * 512 + t;
            int idx  = idx4 << 2;
            if (idx + 3 < e) {
                int4v s4 = __builtin_nontemporal_load(((const int4v*)src) + idx4);
                int4v d4 = __builtin_nontemporal_load(((const int4v*)dst) + idx4);
#pragma unroll
                for (int q = 0; q < 4; q++) {
                    ep[j*4+q] = ((unsigned int)s4[q] << BSHIFT) | (unsigned int)(d4[q] & (NPB-1));
                    eb[j*4+q] = d4[q] >> BSHIFT;
                    atomicAdd(&cnt[eb[j*4+q]], 1);
                }
            } else {
#pragma unroll
                for (int q = 0; q < 4; q++) {
                    int i = idx + q;
                    eb[j*4+q] = -1;
                    if (i < e) {
                        int s = src[i], d = dst[i];
                        ep[j*4+q] = ((unsigned int)s << BSHIFT) | (unsigned int)(d & (NPB-1));
                        eb[j*4+q] = d >> BSHIFT;
                        atomicAdd(&cnt[eb[j*4+q]], 1);
                    }
                }
            }
        }
        __syncthreads();
        if (t < NBUCK_MAX) offs[t] = cnt[t];
        __syncthreads();
        for (int off = 1; off < NBUCK_MAX; off <<= 1) {
            int u = 0;
            if (t < NBUCK_MAX && t >= off) u = offs[t - off];
            __syncthreads();
            if (t < NBUCK_MAX) offs[t] += u;
            __syncthreads();
        }
        if (t < NBUCK_MAX) {
            int ex = offs[t] - cnt[t];
            offs[t] = ex;
            cur[t] = ex;
            if (cnt[t] > 0) base[t] = atomicAdd(&bcur[t], cnt[t]);
        }
        __syncthreads();
#pragma unroll
        for (int j = 0; j < 8; j++) {
            if (eb[j] >= 0) {
                int pos = atomicAdd(&cur[eb[j]], 1);
                sP[pos] = ep[j];
                sB[pos] = (unsigned char)eb[j];
            }
        }
        __syncthreads();
        int nv = min(CHUNK, e - cb);
        for (int i = t; i < nv; i += 512) {
            int b = sB[i];
            pairs[(size_t)b * CAP + base[b] + (i - offs[b])] = sP[i];   // plain store
        }
    } else {
        // ---------------- gemm1 role (27.6KB LDS) ----------------
        short* Wl = (short*)smem;            // [64][72] (transposed W)
        short* Xl = Wl + 64 * 72;            // 2 halves x [64][72]
        const int tile = (int)blockIdx.x - pblocks;
        const int half = t >> 8;
        const int ht   = t & 255;
        const int rowBase = tile * 128 + half * 64;
        short* Xh = Xl + half * 64 * 72;

        for (int i = t; i < 4096; i += 512) {
            int k = i >> 6, nn = i & 63;
            Wl[nn * 72 + k] = (short)f2bf(W[i]);
        }
        for (int i = ht; i < 1024; i += 256) {
            int r = i >> 4, c4 = i & 15;
            int row = rowBase + r;
            float4v v = {0.f, 0.f, 0.f, 0.f};
            if (row < nrows) v = __builtin_nontemporal_load(((const float4v*)(X + (size_t)row * 64)) + c4);
            ushort4 pk = make_ushort4((unsigned short)f2bf(v[0]), (unsigned short)f2bf(v[1]),
                                      (unsigned short)f2bf(v[2]), (unsigned short)f2bf(v[3]));
            *(ushort4*)(Xh + r * 72 + c4 * 4) = pk;
        }
        __syncthreads();

        const int w = ht >> 6;           // wave within half -> 16-row stripe
        const int lane = t & 63;
        const int q = lane >> 4, mn = lane & 15;

        fragf acc0 = {0,0,0,0}, acc1 = {0,0,0,0}, acc2 = {0,0,0,0}, acc3 = {0,0,0,0};
#pragma unroll
        for (int kk = 0; kk < 2; kk++) {
            frag16 a  = *(const frag16*)(Xh + (w * 16 + mn) * 72 + kk * 32 + q * 8);
            frag16 b0 = *(const frag16*)(Wl + ( 0 + mn) * 72 + kk * 32 + q * 8);
            frag16 b1 = *(const frag16*)(Wl + (16 + mn) * 72 + kk * 32 + q * 8);
            frag16 b2 = *(const frag16*)(Wl + (32 + mn) * 72 + kk * 32 + q * 8);
            frag16 b3 = *(const frag16*)(Wl + (48 + mn) * 72 + kk * 32 + q * 8);
            acc0 = __builtin_amdgcn_mfma_f32_16x16x32_bf16(a, b0, acc0, 0, 0, 0);
            acc1 = __builtin_amdgcn_mfma_f32_16x16x32_bf16(a, b1, acc1, 0, 0, 0);
            acc2 = __builtin_amdgcn_mfma_f32_16x16x32_bf16(a, b2, acc2, 0, 0, 0);
            acc3 = __builtin_amdgcn_mfma_f32_16x16x32_bf16(a, b3, acc3, 0, 0, 0);
        }
#pragma unroll
        for (int reg = 0; reg < 4; reg++) {
            int rl = w * 16 + q * 4 + reg;
            int row = rowBase + rl;
            if (row < nrows) {
                size_t ro = (size_t)row * 64;
                Y16[ro +  0 + mn] = (unsigned short)f2bf(acc0[reg]);
                Y16[ro + 16 + mn] = (unsigned short)f2bf(acc1[reg]);
                Y16[ro + 32 + mn] = (unsigned short)f2bf(acc2[reg]);
                Y16[ro + 48 + mn] = (unsigned short)f2bf(acc3[reg]);
            }
        }
    }
}

// ---- per-bucket counting sort + A16 row scale (1024 threads/block) ----
// Emits srcs (slab layout), meta = (beg,end,dinv); then scales this
// bucket's A16 rows by dinv (coalesced, block-local).
__global__ __launch_bounds__(1024) void bucket_csr(const unsigned int* __restrict__ pairs,
                                                   const int* __restrict__ bcur,
                                                   float4* __restrict__ meta,
                                                   int* __restrict__ srcs,
                                                   unsigned int* __restrict__ A,  // [N][32] bf16x2
                                                   int n) {
    __shared__ __align__(16) unsigned int sP[CAP];
    __shared__ int cnt[NPB];
    __shared__ int cur[NPB];
    __shared__ int tsum[NPB];
    __shared__ float dL[NPB];
    const int b = blockIdx.x;
    const int t = threadIdx.x;
    const int nb = b << BSHIFT;
    const int nn = min(NPB, n - nb);
    const size_t slab = (size_t)b * CAP;
    const int cE = bcur[b];

    const int c4 = cE >> 2;
    const uint4v* p4 = (const uint4v*)(pairs + slab);
    for (int i = t; i < c4; i += 1024) ((uint4v*)sP)[i] = p4[i];
    for (int i = (c4 << 2) + t; i < cE; i += 1024) sP[i] = pairs[slab + i];
    if (t < NPB) cnt[t] = 0;
    __syncthreads();

    for (int i = t; i < cE; i += 1024)
        atomicAdd(&cnt[sP[i] & (NPB - 1)], 1);
    __syncthreads();

    int v = (t < NPB) ? cnt[t] : 0;
    if (t < NPB) tsum[t] = v;
    __syncthreads();
    for (int off = 1; off < NPB; off <<= 1) {
        int u = 0;
        if (t < NPB && t >= off) u = tsum[t - off];
        __syncthreads();
        if (t < NPB) tsum[t] += u;
        __syncthreads();
    }
    if (t < NPB) {
        int ex = tsum[t] - v;
        cur[t] = ex;
        float di = rsqrtf((float)v + 1.0f);
        dL[t] = di;
        if (t < nn) {
            int g = (int)slab + ex;
            meta[nb + t] = make_float4(__int_as_float(g), __int_as_float(g + v), di, 0.f);
        }
    }
    __syncthreads();
    for (int i = t; i < cE; i += 1024) {
        unsigned int p = sP[i];
        int pos = atomicAdd(&cur[p & (NPB - 1)], 1);
        srcs[slab + pos] = (int)(p >> BSHIFT);                  // plain store
    }
    // ---- scale tail: A16 rows of this bucket *= dinv[row] ----
    const int tot = nn << 5;                                    // nn * 32 dwords
    for (int i = t; i < tot; i += 1024) {
        int r = i >> 5, c = i & 31;
        size_t idx = ((size_t)(nb + r) << 5) + c;
        unsigned int u = A[idx];
        float d = dL[r];
        A[idx] = f2bf(bfl(u) * d) | (f2bf(bfh(u) * d) << 16);
    }
}

// ---- Y16[N,64](bf16) = (X16 @ W) * dinv[row], via 16x16x32 bf16 MFMA ----
// (standalone, used for layer 2; input bf16, pre-scales by dinv)
__global__ __launch_bounds__(256) void gemm_mfma_bf16(const unsigned short* __restrict__ X,
                                                      const float* __restrict__ W,
                                                      const float4* __restrict__ meta,
                                                      unsigned short* __restrict__ Y16,
                                                      int nrows) {
    __shared__ __align__(16) short Xl[64 * 72];
    __shared__ __align__(16) short Wl[64 * 72];   // Wl[n][k] (transposed)
    __shared__ float dl[64];
    const int tid = threadIdx.x;
    const int rowBase = blockIdx.x * 64;

    for (int i = tid; i < 4096; i += 256) {
        int k = i >> 6, nn = i & 63;
        Wl[nn * 72 + k] = (short)f2bf(W[i]);
    }
    for (int i = tid; i < 512; i += 256) {
        int r = i >> 3, c8 = i & 7;
        int row = rowBase + r;
        uint4v v = {0, 0, 0, 0};
        if (row < nrows) v = *(((const uint4v*)(X + (size_t)row * 64)) + c8);
        *(uint4v*)(Xl + r * 72 + c8 * 8) = v;
    }
    if (tid < 64) {
        int row = rowBase + tid;
        dl[tid] = (row < nrows) ? meta[row].z : 0.f;
    }
    __syncthreads();

    const int w = tid >> 6;          // wave id -> 16-row stripe
    const int lane = tid & 63;
    const int q = lane >> 4, mn = lane & 15;

    fragf acc0 = {0,0,0,0}, acc1 = {0,0,0,0}, acc2 = {0,0,0,0}, acc3 = {0,0,0,0};
#pragma unroll
    for (int kk = 0; kk < 2; kk++) {
        frag16 a  = *(const frag16*)(Xl + (w * 16 + mn) * 72 + kk * 32 + q * 8);
        frag16 b0 = *(const frag16*)(Wl + ( 0 + mn) * 72 + kk * 32 + q * 8);
        frag16 b1 = *(const frag16*)(Wl + (16 + mn) * 72 + kk * 32 + q * 8);
        frag16 b2 = *(const frag16*)(Wl + (32 + mn) * 72 + kk * 32 + q * 8);
        frag16 b3 = *(const frag16*)(Wl + (48 + mn) * 72 + kk * 32 + q * 8);
        acc0 = __builtin_amdgcn_mfma_f32_16x16x32_bf16(a, b0, acc0, 0, 0, 0);
        acc1 = __builtin_amdgcn_mfma_f32_16x16x32_bf16(a, b1, acc1, 0, 0, 0);
        acc2 = __builtin_amdgcn_mfma_f32_16x16x32_bf16(a, b2, acc2, 0, 0, 0);
        acc3 = __builtin_amdgcn_mfma_f32_16x16x32_bf16(a, b3, acc3, 0, 0, 0);
    }
#pragma unroll
    for (int reg = 0; reg < 4; reg++) {
        int rl = w * 16 + q * 4 + reg;
        int row = rowBase + rl;
        if (row < nrows) {
            float di = dl[rl];
            size_t ro = (size_t)row * 64;
            Y16[ro +  0 + mn] = (unsigned short)f2bf(acc0[reg] * di);
            Y16[ro + 16 + mn] = (unsigned short)f2bf(acc1[reg] * di);
            Y16[ro + 32 + mn] = (unsigned short)f2bf(acc2[reg] * di);
            Y16[ro + 48 + mn] = (unsigned short)f2bf(acc3[reg] * di);
        }
    }
}

// ---- gather: 2 nodes/wave, prescaled rows, 8-deep MLP, no barrier ----
// OUT16: write bf16 (layer 1, feeds gemm2); else fp32 NT (final output).
template<bool OUT16>
__global__ __launch_bounds__(256) void gather_nodes(const unsigned short* __restrict__ XW,
                                                    const float4* __restrict__ meta,
                                                    const int* __restrict__ srcs,
                                                    const float* __restrict__ bias,
                                                    void* __restrict__ outp, int n) {
    int wv   = (blockIdx.x * 256 + threadIdx.x) >> 6;
    int lane = threadIdx.x & 63;
    int node = wv * 2 + (lane >> 5);
    int fl   = lane & 31;                  // feature pair: 2*fl, 2*fl+1
    if (node >= n) return;
    const unsigned int* Xp = (const unsigned int*)XW;   // [N][32] bf16x2
    float4 mv = meta[node];
    int beg = __float_as_int(mv.x), end = __float_as_int(mv.y);
    float di = mv.z;
    float2 bv = *(const float2*)(bias + fl * 2);
    unsigned int sv = Xp[(size_t)node * 32 + fl];
    float acc0 = bfl(sv);   // self-loop (row already carries dinv[node])
    float acc1 = bfh(sv);

    int e = beg;
    for (; e + 8 <= end; e += 8) {
        int s0 = srcs[e],     s1 = srcs[e + 1], s2 = srcs[e + 2], s3 = srcs[e + 3];
        int s4 = srcs[e + 4], s5 = srcs[e + 5], s6 = srcs[e + 6], s7 = srcs[e + 7];
        unsigned int v0 = Xp[(size_t)s0 * 32 + fl];
        unsigned int v1 = Xp[(size_t)s1 * 32 + fl];
        unsigned int v2 = Xp[(size_t)s2 * 32 + fl];
        unsigned int v3 = Xp[(size_t)s3 * 32 + fl];
        unsigned int v4 = Xp[(size_t)s4 * 32 + fl];
        unsigned int v5 = Xp[(size_t)s5 * 32 + fl];
        unsigned int v6 = Xp[(size_t)s6 * 32 + fl];
        unsigned int v7 = Xp[(size_t)s7 * 32 + fl];
        acc0 += bfl(v0); acc1 += bfh(v0);
        acc0 += bfl(v1); acc1 += bfh(v1);
        acc0 += bfl(v2); acc1 += bfh(v2);
        acc0 += bfl(v3); acc1 += bfh(v3);
        acc0 += bfl(v4); acc1 += bfh(v4);
        acc0 += bfl(v5); acc1 += bfh(v5);
        acc0 += bfl(v6); acc1 += bfh(v6);
        acc0 += bfl(v7); acc1 += bfh(v7);
    }
    for (; e + 4 <= end; e += 4) {
        int s0 = srcs[e], s1 = srcs[e + 1], s2 = srcs[e + 2], s3 = srcs[e + 3];
        unsigned int v0 = Xp[(size_t)s0 * 32 + fl];
        unsigned int v1 = Xp[(size_t)s1 * 32 + fl];
        unsigned int v2 = Xp[(size_t)s2 * 32 + fl];
        unsigned int v3 = Xp[(size_t)s3 * 32 + fl];
        acc0 += bfl(v0); acc1 += bfh(v0);
        acc0 += bfl(v1); acc1 += bfh(v1);
        acc0 += bfl(v2); acc1 += bfh(v2);
        acc0 += bfl(v3); acc1 += bfh(v3);
    }
    for (; e < end; e++) {
        int s = srcs[e];
        unsigned int v = Xp[(size_t)s * 32 + fl];
        acc0 += bfl(v); acc1 += bfh(v);
    }
    float r0 = fmaxf(acc0 * di + bv.x, 0.f);
    float r1 = fmaxf(acc1 * di + bv.y, 0.f);
    if (OUT16) {
        ((unsigned int*)outp)[(size_t)node * 32 + fl] = f2bf(r0) | (f2bf(r1) << 16);
    } else {
        // coalesced full-line single-use stream -> NT ok
        float* op = (float*)outp + (size_t)node * 64 + fl * 2;
        __builtin_nontemporal_store(r0, op);
        __builtin_nontemporal_store(r1, op + 1);
    }
}

extern "C" void kernel_launch(void* const* d_in, const int* in_sizes, int n_in,
                              void* d_out, int out_size, void* d_ws, size_t ws_size,
                              hipStream_t stream) {
    const float* x  = (const float*)d_in[0];
    const int*   ei = (const int*)d_in[1];
    const float* W1 = (const float*)d_in[2];
    const float* b1 = (const float*)d_in[3];
    const float* W2 = (const float*)d_in[4];
    const float* b2 = (const float*)d_in[5];
    float* out = (float*)d_out;

    const int N = in_sizes[0] / 64;
    const int E = in_sizes[1] / 2;
    const int* srcA = ei;
    const int* dstA = ei + E;
    const int K = (N + NPB - 1) >> BSHIFT;   // 196

    char* ws = (char*)d_ws;
    auto alloc = [&](size_t bytes) { char* p = ws; ws += (bytes + 255) & ~(size_t)255; return p; };
    unsigned short* A16 = (unsigned short*)alloc((size_t)N * 64 * 2);  // XW1 bf16 (scaled by csr)
    unsigned short* B16 = (unsigned short*)alloc((size_t)N * 64 * 2);  // h1 bf16
    float4* meta  = (float4*)alloc((size_t)N * 16);
    int*   srcs_sorted = (int*)alloc((size_t)K * CAP * 4);             // slab layout
    unsigned int* pairs = (unsigned int*)alloc((size_t)K * CAP * 4);   // own buffer (gemm1 concurrent)
    int*   bcur   = (int*)  alloc(NBUCK_MAX * 4);

    const int pblocks = (E + CHUNK - 1) / CHUNK;     // 391
    const int gblocks = (N + 127) / 128;             // 782
    const int nodeBlocks = (N + 7) / 8;              // 4 waves/block x 2 nodes/wave

    // ---- CSR build || layer-1 gemm (fused; gemm1 output unscaled) ----
    hipMemsetAsync(bcur, 0, NBUCK_MAX * 4, stream);
    fused_build_gemm1<<<pblocks + gblocks, 512, 0, stream>>>(srcA, dstA, bcur, pairs, E,
                                                             pblocks, x, W1, A16, N);
    // ---- counting sort + A16 *= dinv[row] ----
    bucket_csr<<<K, 1024, 0, stream>>>(pairs, bcur, meta, srcs_sorted,
                                       (unsigned int*)A16, N);
    // ---- layer 1 gather -> B16 ----
    gather_nodes<true><<<nodeBlocks, 256, 0, stream>>>(A16, meta, srcs_sorted, b1, B16, N);
    // ---- layer 2 gemm (B16 @ W2) * dinv -> A16 (buffer reuse) ----
    gemm_mfma_bf16<<<(N + 63) / 64, 256, 0, stream>>>(B16, W2, meta, A16, N);
    // ---- layer 2 gather -> fp32 out ----
    gather_nodes<false><<<nodeBlocks, 256, 0, stream>>>(A16, meta, srcs_sorted, b2, out, N);
}